// Round 6
// baseline (1160.240 us; speedup 1.0000x reference)
//
#include <hip/hip_runtime.h>
#include <hip/hip_bf16.h>
#include <cstdint>
#include <cstddef>

// ---------------------------------------------------------------------------
// SwinLikeBlock, MI355X gfx950. Inputs f32, OUTPUT f32 (reference dtype —
// round-6 fix; rounds 4/5 wrote bf16 and the f32 readback shuffled values,
// explaining the bit-identical 7.67 error across different implementations).
// N=8, H=W=112, C=256, WS=7 -> 2048 windows x 49 tok, 8 heads x d=32,
// hidden=1024, T=100352.
//
// Structure (round 5, unchanged): ws = 1.5 MiB converted bf16 weights only.
//   conv_k x4 : W_qkv/W_proj/W_fc1/W_fc2 f32 -> bf16 in ws
//   attn_half_k (1 block/window): LN1 -> y(LDS) -> qkv GEMM (B-frags streamed
//       from global bf16 weights) -> qkv(LDS) -> online-softmax attention ->
//       proj GEMM + b_proj + x residual -> d_out (f32)
//   mlp_half_k (1 block/64 tokens): LN2(f32 in) -> z(LDS) -> 4x[fc1 chunk ->
//       GELU -> h(LDS) -> fc2 partial-K] -> + b_fc2 + residual -> d_out f32 RMW
// LDS 16B-group XOR swizzle: group g of row r stored at (g&~7)|((g^r)&7).
// ---------------------------------------------------------------------------

typedef __bf16 bf16x8 __attribute__((ext_vector_type(8)));
typedef float f32x4 __attribute__((ext_vector_type(4)));

__device__ __forceinline__ float bf2f_lo(uint32_t u){ union{uint32_t u;float f;}c;c.u=u<<16;return c.f;}
__device__ __forceinline__ float bf2f_hi(uint32_t u){ union{uint32_t u;float f;}c;c.u=u&0xffff0000u;return c.f;}
__device__ __forceinline__ unsigned short f2bf(float f){
    union{float f;uint32_t u;}c;c.f=f;uint32_t u=c.u;u+=0x7fffu+((u>>16)&1u);return (unsigned short)(u>>16);}
__device__ __forceinline__ float gelu_f(float x){ return 0.5f*x*(1.0f+erff(x*0.70710678118654752f)); }
__device__ __forceinline__ int swz(int row,int g){ return (g & ~7) | ((g ^ row) & 7); }
__device__ __forceinline__ void unpack8(uint4 u, float* f){
    f[0]=bf2f_lo(u.x); f[1]=bf2f_hi(u.x); f[2]=bf2f_lo(u.y); f[3]=bf2f_hi(u.y);
    f[4]=bf2f_lo(u.z); f[5]=bf2f_hi(u.z); f[6]=bf2f_lo(u.w); f[7]=bf2f_hi(u.w);
}

// f32 -> bf16 convert, n4 = count/4
__global__ __launch_bounds__(256) void conv_k(
    const float* __restrict__ src, unsigned short* __restrict__ dst, int n4)
{
    int i = blockIdx.x * 256 + threadIdx.x;
    if (i >= n4) return;
    float4 v = *(const float4*)(src + (size_t)i * 4);
    uint2 o;
    o.x = (uint32_t)f2bf(v.x) | ((uint32_t)f2bf(v.y) << 16);
    o.y = (uint32_t)f2bf(v.z) | ((uint32_t)f2bf(v.w) << 16);
    *(uint2*)(dst + (size_t)i * 4) = o;
}

// ---------------------------------------------------------------------------
// Kernel A: fused LN1 + qkv + window attention + proj + residual -> f32 out.
// One block (256 thr, 4 waves) per window. LDS: yb 32KB + qk 96KB.
// ---------------------------------------------------------------------------
__global__ __launch_bounds__(256) void attn_half_k(
    const float* __restrict__ x, const float* __restrict__ g1, const float* __restrict__ b1,
    const unsigned short* __restrict__ Wqkv, const float* __restrict__ bqkv,
    const unsigned short* __restrict__ Wproj, const float* __restrict__ bproj,
    float* __restrict__ out)
{
    __shared__ __align__(16) unsigned short yb[64 * 256];
    __shared__ __align__(16) unsigned short qk[64 * 768];
    const int t = threadIdx.x, lane = t & 63, w = t >> 6;
    const int quad = lane >> 4, l16 = lane & 15;
    const int widx = blockIdx.x;               // 0..2047
    const int img = widx >> 8, wi = widx & 255;
    const int wy = wi >> 4, wx = wi & 15;
    const size_t ibase = (size_t)img * 12544;

    // ---- LN1 into yb (swizzled); one wave per token ----
    for (int tok = w; tok < 49; tok += 4) {
        int r = tok / 7, c = tok - r * 7;
        size_t gtok = ibase + (size_t)(wy * 7 + r) * 112 + (wx * 7 + c);
        float4 v = *(const float4*)(x + gtok * 256 + lane * 4);
        float s = v.x + v.y + v.z + v.w;
        float q = v.x*v.x + v.y*v.y + v.z*v.z + v.w*v.w;
        #pragma unroll
        for (int o = 32; o > 0; o >>= 1) { s += __shfl_xor(s, o); q += __shfl_xor(q, o); }
        float mean = s * (1.f/256.f), var = q * (1.f/256.f) - mean * mean;
        float inv = rsqrtf(var + 1e-5f);
        float4 gv = *(const float4*)(g1 + lane * 4);
        float4 bv = *(const float4*)(b1 + lane * 4);
        uint2 pk;
        pk.x = (uint32_t)f2bf((v.x-mean)*inv*gv.x+bv.x) | ((uint32_t)f2bf((v.y-mean)*inv*gv.y+bv.y) << 16);
        pk.y = (uint32_t)f2bf((v.z-mean)*inv*gv.z+bv.z) | ((uint32_t)f2bf((v.w-mean)*inv*gv.w+bv.w) << 16);
        *(uint2*)&yb[tok*256 + swz(tok, lane >> 1)*8 + (lane & 1)*4] = pk;
    }
    {   // zero pad rows 49..63
        uint2 z2; z2.x = 0u; z2.y = 0u;
        for (int i = t; i < 960; i += 256) {
            int row = 49 + (i >> 6), c4 = (i & 63) * 4;
            *(uint2*)&yb[row*256 + c4] = z2;
        }
    }
    __syncthreads();

    // ---- qkv GEMM: yb(64x256) @ Wqkv(768x256)^T + b -> qk (bf16, swizzled) ----
    for (int nc = 0; nc < 4; ++nc) {
        const int n0 = nc * 192 + w * 48;
        f32x4 acc[4][3] = {};
        #pragma unroll
        for (int ks = 0; ks < 8; ++ks) {
            bf16x8 af[4], bfr[3];
            #pragma unroll
            for (int mt = 0; mt < 4; ++mt) {
                int m = mt * 16 + l16;
                af[mt] = *(const bf16x8*)&yb[m*256 + swz(m, ks*4 + quad)*8];
            }
            #pragma unroll
            for (int nt = 0; nt < 3; ++nt) {
                int n = n0 + nt * 16 + l16;
                bfr[nt] = *(const bf16x8*)(Wqkv + (size_t)n*256 + ks*32 + quad*8);
            }
            #pragma unroll
            for (int mt = 0; mt < 4; ++mt)
                #pragma unroll
                for (int nt = 0; nt < 3; ++nt)
                    acc[mt][nt] = __builtin_amdgcn_mfma_f32_16x16x32_bf16(
                        af[mt], bfr[nt], acc[mt][nt], 0, 0, 0);
        }
        #pragma unroll
        for (int mt = 0; mt < 4; ++mt)
            #pragma unroll
            for (int nt = 0; nt < 3; ++nt) {
                int col = n0 + nt * 16 + l16;
                float bb = bqkv[col];
                #pragma unroll
                for (int r = 0; r < 4; ++r) {
                    int row = mt * 16 + quad * 4 + r;
                    qk[row*768 + swz(row, col >> 3)*8 + (col & 7)] = f2bf(acc[mt][nt][r] + bb);
                }
            }
    }
    __syncthreads();

    // ---- attention: wave w -> heads w and w+4; lane l<49 owns query l ----
    const float scale = 0.17677669529663687f;   // 32^-0.5
    #pragma unroll
    for (int hh = 0; hh < 2; ++hh) {
        const int h = w + hh * 4;
        const int l = lane;
        if (l < 49) {
            float qv[32];
            #pragma unroll
            for (int j = 0; j < 4; ++j) {
                uint4 u = *(const uint4*)&qk[l*768 + swz(l, h*4 + j)*8];
                unpack8(u, &qv[j*8]);
            }
            float mx = -1e30f, lsum = 0.f;
            float o[32];
            #pragma unroll
            for (int i = 0; i < 32; ++i) o[i] = 0.f;
            for (int m = 0; m < 49; ++m) {      // online softmax; k/v broadcast
                float kv[32];
                #pragma unroll
                for (int j = 0; j < 4; ++j) {
                    uint4 u = *(const uint4*)&qk[m*768 + swz(m, 32 + h*4 + j)*8];
                    unpack8(u, &kv[j*8]);
                }
                float d = 0.f;
                #pragma unroll
                for (int i = 0; i < 32; ++i) d += qv[i] * kv[i];
                d *= scale;
                float nm = fmaxf(mx, d);
                float alpha = __expf(mx - nm);
                float p = __expf(d - nm);
                lsum = lsum * alpha + p;
                float vv[32];
                #pragma unroll
                for (int j = 0; j < 4; ++j) {
                    uint4 u = *(const uint4*)&qk[m*768 + swz(m, 64 + h*4 + j)*8];
                    unpack8(u, &vv[j*8]);
                }
                #pragma unroll
                for (int i = 0; i < 32; ++i) o[i] = o[i] * alpha + p * vv[i];
                mx = nm;
            }
            float inv = 1.f / lsum;
            #pragma unroll
            for (int j = 0; j < 4; ++j) {       // attn out -> yb (channel h*32+d)
                uint4 pk;
                pk.x = (uint32_t)f2bf(o[j*8+0]*inv) | ((uint32_t)f2bf(o[j*8+1]*inv) << 16);
                pk.y = (uint32_t)f2bf(o[j*8+2]*inv) | ((uint32_t)f2bf(o[j*8+3]*inv) << 16);
                pk.z = (uint32_t)f2bf(o[j*8+4]*inv) | ((uint32_t)f2bf(o[j*8+5]*inv) << 16);
                pk.w = (uint32_t)f2bf(o[j*8+6]*inv) | ((uint32_t)f2bf(o[j*8+7]*inv) << 16);
                *(uint4*)&yb[l*256 + swz(l, h*4 + j)*8] = pk;
            }
        }
    }
    __syncthreads();

    // ---- proj: yb @ Wproj^T + b_proj + x -> out (f32) ----
    {
        const int n0 = w * 64;
        f32x4 acc[4][4] = {};
        #pragma unroll
        for (int ks = 0; ks < 8; ++ks) {
            bf16x8 af[4], bfr[4];
            #pragma unroll
            for (int mt = 0; mt < 4; ++mt) {
                int m = mt * 16 + l16;
                af[mt] = *(const bf16x8*)&yb[m*256 + swz(m, ks*4 + quad)*8];
            }
            #pragma unroll
            for (int nt = 0; nt < 4; ++nt) {
                int n = n0 + nt * 16 + l16;
                bfr[nt] = *(const bf16x8*)(Wproj + (size_t)n*256 + ks*32 + quad*8);
            }
            #pragma unroll
            for (int mt = 0; mt < 4; ++mt)
                #pragma unroll
                for (int nt = 0; nt < 4; ++nt)
                    acc[mt][nt] = __builtin_amdgcn_mfma_f32_16x16x32_bf16(
                        af[mt], bfr[nt], acc[mt][nt], 0, 0, 0);
        }
        #pragma unroll
        for (int mt = 0; mt < 4; ++mt)
            #pragma unroll
            for (int r = 0; r < 4; ++r) {
                int row = mt * 16 + quad * 4 + r;
                if (row < 49) {
                    int rr = row / 7, cc = row - rr * 7;
                    size_t gtok = ibase + (size_t)(wy * 7 + rr) * 112 + (wx * 7 + cc);
                    #pragma unroll
                    for (int nt = 0; nt < 4; ++nt) {
                        int col = n0 + nt * 16 + l16;
                        out[gtok * 256 + col] = acc[mt][nt][r] + bproj[col] + x[gtok * 256 + col];
                    }
                }
            }
    }
}

// ---------------------------------------------------------------------------
// Kernel B: fused LN2 + fc1 + GELU + fc2 + residual, in-place f32 RMW on out.
// One block (256 thr, 4 waves) per 64 tokens. LDS: zb + hb = 64 KB.
// ---------------------------------------------------------------------------
__global__ __launch_bounds__(256) void mlp_half_k(
    const float* __restrict__ g2, const float* __restrict__ b2,
    const unsigned short* __restrict__ W1, const float* __restrict__ bf1,
    const unsigned short* __restrict__ W2, const float* __restrict__ bf2,
    float* __restrict__ out)
{
    __shared__ __align__(16) unsigned short zb[64 * 256];
    __shared__ __align__(16) unsigned short hb[64 * 256];
    const int t = threadIdx.x, lane = t & 63, w = t >> 6;
    const int quad = lane >> 4, l16 = lane & 15;
    const size_t m0 = (size_t)blockIdx.x * 64;

    // ---- LN2 from f32 out into zb ----
    for (int tok = w; tok < 64; tok += 4) {
        size_t row = m0 + tok;
        float4 v = *(const float4*)&out[row*256 + lane*4];
        float s = v.x+v.y+v.z+v.w, q = v.x*v.x+v.y*v.y+v.z*v.z+v.w*v.w;
        #pragma unroll
        for (int o = 32; o > 0; o >>= 1) { s += __shfl_xor(s, o); q += __shfl_xor(q, o); }
        float mean = s*(1.f/256.f), var = q*(1.f/256.f) - mean*mean;
        float inv = rsqrtf(var + 1e-5f);
        float4 gv = *(const float4*)(g2 + lane*4);
        float4 bv = *(const float4*)(b2 + lane*4);
        uint2 pk;
        pk.x = (uint32_t)f2bf((v.x-mean)*inv*gv.x+bv.x) | ((uint32_t)f2bf((v.y-mean)*inv*gv.y+bv.y) << 16);
        pk.y = (uint32_t)f2bf((v.z-mean)*inv*gv.z+bv.z) | ((uint32_t)f2bf((v.w-mean)*inv*gv.w+bv.w) << 16);
        *(uint2*)&zb[tok*256 + swz(tok, lane >> 1)*8 + (lane & 1)*4] = pk;
    }
    __syncthreads();

    f32x4 acc2[4][4] = {};
    for (int c = 0; c < 4; ++c) {                 // hidden chunks of 256
        const int hc0 = c * 256;
        f32x4 acc1[4][4] = {};
        #pragma unroll
        for (int ks = 0; ks < 8; ++ks) {          // fc1: K = 256
            bf16x8 af[4], bfr[4];
            #pragma unroll
            for (int mt = 0; mt < 4; ++mt) {
                int m = mt * 16 + l16;
                af[mt] = *(const bf16x8*)&zb[m*256 + swz(m, ks*4 + quad)*8];
            }
            #pragma unroll
            for (int nt = 0; nt < 4; ++nt) {
                int n = hc0 + w * 64 + nt * 16 + l16;
                bfr[nt] = *(const bf16x8*)(W1 + (size_t)n*256 + ks*32 + quad*8);
            }
            #pragma unroll
            for (int mt = 0; mt < 4; ++mt)
                #pragma unroll
                for (int nt = 0; nt < 4; ++nt)
                    acc1[mt][nt] = __builtin_amdgcn_mfma_f32_16x16x32_bf16(
                        af[mt], bfr[nt], acc1[mt][nt], 0, 0, 0);
        }
        __syncthreads();                          // prev chunk's hb reads done
        #pragma unroll
        for (int mt = 0; mt < 4; ++mt)
            #pragma unroll
            for (int nt = 0; nt < 4; ++nt) {
                int lc = w * 64 + nt * 16 + l16;
                float bb = bf1[hc0 + lc];
                #pragma unroll
                for (int r = 0; r < 4; ++r) {
                    int row = mt * 16 + quad * 4 + r;
                    hb[row*256 + swz(row, lc >> 3)*8 + (lc & 7)] =
                        f2bf(gelu_f(acc1[mt][nt][r] + bb));
                }
            }
        __syncthreads();
        #pragma unroll
        for (int ks = 0; ks < 8; ++ks) {          // fc2 partial-K
            bf16x8 af[4], bfr[4];
            #pragma unroll
            for (int mt = 0; mt < 4; ++mt) {
                int m = mt * 16 + l16;
                af[mt] = *(const bf16x8*)&hb[m*256 + swz(m, ks*4 + quad)*8];
            }
            #pragma unroll
            for (int nt = 0; nt < 4; ++nt) {
                int n = w * 64 + nt * 16 + l16;
                bfr[nt] = *(const bf16x8*)(W2 + (size_t)n*1024 + hc0 + ks*32 + quad*8);
            }
            #pragma unroll
            for (int mt = 0; mt < 4; ++mt)
                #pragma unroll
                for (int nt = 0; nt < 4; ++nt)
                    acc2[mt][nt] = __builtin_amdgcn_mfma_f32_16x16x32_bf16(
                        af[mt], bfr[nt], acc2[mt][nt], 0, 0, 0);
        }
    }
    // ---- epilogue: + b_fc2 + residual, f32 in-place ----
    #pragma unroll
    for (int mt = 0; mt < 4; ++mt)
        #pragma unroll
        for (int nt = 0; nt < 4; ++nt) {
            int col = w * 64 + nt * 16 + l16;
            float bb = bf2[col];
            #pragma unroll
            for (int r = 0; r < 4; ++r) {
                size_t row = m0 + mt * 16 + quad * 4 + r;
                out[row*256 + col] = acc2[mt][nt][r] + bb + out[row*256 + col];
            }
        }
}

// ---------------------------------------------------------------------------
extern "C" void kernel_launch(void* const* d_in, const int* in_sizes, int n_in,
                              void* d_out, int out_size, void* d_ws, size_t ws_size,
                              hipStream_t stream)
{
    const float* x      = (const float*)d_in[0];
    // d_in[1]=H, d_in[2]=W : compile-time constants (112).
    const float* g1     = (const float*)d_in[3];
    const float* b1     = (const float*)d_in[4];
    const float* w_qkv  = (const float*)d_in[5];
    const float* b_qkv  = (const float*)d_in[6];
    const float* w_proj = (const float*)d_in[7];
    const float* b_proj = (const float*)d_in[8];
    const float* g2     = (const float*)d_in[9];
    const float* b2     = (const float*)d_in[10];
    const float* w_fc1  = (const float*)d_in[11];
    const float* b_fc1  = (const float*)d_in[12];
    const float* w_fc2  = (const float*)d_in[13];
    const float* b_fc2  = (const float*)d_in[14];
    float* out = (float*)d_out;                      // f32 output

    // ws: converted bf16 weights only — 786432 elems = 1.5 MiB
    unsigned short* cWqkv  = (unsigned short*)d_ws;  // 196608
    unsigned short* cWproj = cWqkv  + 196608;        // 65536
    unsigned short* cWfc1  = cWproj + 65536;         // 262144
    unsigned short* cWfc2  = cWfc1  + 262144;        // 262144

    conv_k<<<192, 256, 0, stream>>>(w_qkv,  cWqkv,  49152);
    conv_k<<<64,  256, 0, stream>>>(w_proj, cWproj, 16384);
    conv_k<<<256, 256, 0, stream>>>(w_fc1,  cWfc1,  65536);
    conv_k<<<256, 256, 0, stream>>>(w_fc2,  cWfc2,  65536);

    attn_half_k<<<2048, 256, 0, stream>>>(x, g1, b1, cWqkv, b_qkv, cWproj, b_proj, out);
    mlp_half_k<<<1568, 256, 0, stream>>>(g2, b2, cWfc1, b_fc1, cWfc2, b_fc2, out);
}